// Round 11
// baseline (224.799 us; speedup 1.0000x reference)
//
#include <hip/hip_runtime.h>
#include <math.h>

// 2D 16-NN distances, N=16384, exact, uniform-grid binned, fixed bounds.
// 3 dispatches: memset(counts+bar) -> build(fused count/scan/scatter, 64
// blocks + device-atomic grid barriers) -> query.
// Query: each 16-LANE GROUP owns ONE query (4 queries/wave, fully decoupled):
// own rect, own R, own count-first sizing (TARGET pts), ONE rect scan with
// group-parallel span prefetch, own stop check (>=17 pts incl self within
// R*HMIN <= dist to any unvisited cell), incremental delta strips on failure.
// Divergent group loops cost max-not-sum within the wave -> tail = worst
// single query, not a 4-query union. Per-lane sorted top-17 via med3 chain;
// self (d2=0) dropped at output == reference idx[:,1:].

#define G      128
#define NC     (G * G)
#define NK     16
#define KP1    17
#define QPW    4
#define PARTS  16
#define BLOCK  256
#define TARGET 48
#define NBB    64      // build blocks (co-resident on 256 CUs -> barrier safe)

#define BX0   (-5.5f)
#define BY0   (-5.5f)
#define BEXT  (11.0f)
#define IH    ((float)G * (1.0f - 1e-5f) / BEXT)   // cells per unit
#define HMIN  (BEXT / ((float)G * (1.0f - 1e-5f))) // cell dimension

// ws layout (bytes), total 328008 (< round-4's proven 393344)
#define WS_COUNTS   0        // 16384 i32 (atomically counted, then cursor)
#define WS_BAR      65536    // 16 i32 barrier slots
#define WS_BSUM     65600    // 64 i32 block sums
#define WS_OFFSETS  65856    // 16385 i32
#define WS_SXY      131400   // 16384 float2
#define WS_SIDX     262472   // 16384 i32

__device__ __forceinline__ int clampi(int v, int lo, int hi) {
    return v < lo ? lo : (v > hi ? hi : v);
}
__device__ __forceinline__ int cell_of(float x, float y) {
    int cx = clampi((int)((x - BX0) * IH), 0, G - 1);
    int cy = clampi((int)((y - BY0) * IH), 0, G - 1);
    int xx = (cy & 1) ? (G - 1 - cx) : cx;     // serpentine
    return cy * G + xx;
}

// device-scope spin barrier; NBB blocks, one slot per use. Slots pre-zeroed.
__device__ __forceinline__ void gbar(int* bar, int slot) {
    __syncthreads();
    __threadfence();                 // release my writes
    if (threadIdx.x == 0) {
        atomicAdd(&bar[slot], 1);
        while (__hip_atomic_load(&bar[slot], __ATOMIC_RELAXED,
                                 __HIP_MEMORY_SCOPE_AGENT) < NBB) {
            __builtin_amdgcn_s_sleep(2);
        }
    }
    __syncthreads();
    __threadfence();                 // acquire others' writes
}

// ---- fused build: count -> hierarchical scan -> scatter (one dispatch) ----
__global__ __launch_bounds__(1024) void build_kernel(const float* __restrict__ p, int n,
                                                     int* __restrict__ counts,
                                                     int* __restrict__ bar,
                                                     int* __restrict__ bsum,
                                                     int* __restrict__ offsets,
                                                     float2* __restrict__ sxy,
                                                     int* __restrict__ sidx) {
    __shared__ int sm[256];
    const int t   = threadIdx.x;
    const int gid = blockIdx.x * 1024 + t;

    // ph1: count
    float x = 0.f, y = 0.f; int cell = 0;
    const bool have = (gid < n);
    if (have) {
        x = p[3 * gid]; y = p[3 * gid + 1];
        cell = cell_of(x, y);
        atomicAdd(&counts[cell], 1);
    }
    gbar(bar, 0);

    // ph2: block-local scan of 256 cells (cells [b*256, b*256+256))
    const int cbase = blockIdx.x * 256;
    int v = 0;
    if (t < 256) { v = counts[cbase + t]; sm[t] = v; }
    __syncthreads();
    for (int off = 1; off < 256; off <<= 1) {
        int x2 = 0;
        if (t < 256 && t >= off) x2 = sm[t - off];
        __syncthreads();
        if (t < 256) sm[t] += x2;
        __syncthreads();
    }
    const int pre = (t < 256) ? (sm[t] - v) : 0;   // exclusive within block
    if (t == 0) bsum[blockIdx.x] = sm[255];        // block total
    gbar(bar, 1);

    // ph3: block 0 scans the 64 block sums (single wave)
    if (blockIdx.x == 0 && t < 64) {
        int bv = bsum[t], inc = bv;
#pragma unroll
        for (int off = 1; off < 64; off <<= 1) {
            int x2 = __shfl_up(inc, off);
            if (t >= off) inc += x2;
        }
        bsum[t] = inc - bv;                        // exclusive
        if (t == 63) offsets[NC] = inc;            // == n
    }
    gbar(bar, 2);

    // ph4: write offsets and cursor init
    if (t < 256) {
        int o = pre + bsum[blockIdx.x];
        offsets[cbase + t] = o;
        counts[cbase + t] = o;                     // counts becomes cursor
    }
    gbar(bar, 3);

    // ph5: scatter
    if (have) {
        int pos = atomicAdd(&counts[cell], 1);
        sxy[pos] = make_float2(x, y);
        sidx[pos] = gid;
    }
}

// ---- query: one 16-lane group per query, fully decoupled ----
__global__ __launch_bounds__(BLOCK) void knn_query(const int* __restrict__ offsets,
                                                   const float2* __restrict__ sxy,
                                                   const int* __restrict__ sidx,
                                                   float* __restrict__ out, int n) {
    __shared__ float mrg[4][QPW][PARTS][KP1];

    const int t    = threadIdx.x;
    const int lane = t & 63;
    const int wv   = t >> 6;
    const int ql   = lane >> 4;      // group (query slot) 0..3
    const int part = lane & 15;
    const int gb   = ql << 4;        // group base lane
    const int sq   = (blockIdx.x * 4 + wv) * QPW + ql;
    const int sqc  = (sq < n) ? sq : (n - 1);

    const float2 qp = sxy[sqc];
    const float qx = qp.x, qy = qp.y;
    const int cx = clampi((int)((qx - BX0) * IH), 0, G - 1);
    const int cy = clampi((int)((qy - BY0) * IH), 0, G - 1);

    float b[KP1];
#pragma unroll
    for (int i = 0; i < KP1; ++i) b[i] = 3.0e38f;

    // group-parallel scan of cell rect [ylo..yhi]x[xlo..xhi]
    auto scan_rect = [&](int ylo, int yhi, int xlo, int xhi) {
        if (ylo > yhi || xlo > xhi) return;
        const int nrows = yhi - ylo + 1;
        for (int rb = 0; rb < nrows; rb += 16) {
            const int rem = min(nrows - rb, 16);   // group-uniform
            int s0 = 0, e0 = 0;
            if (part < rem) {
                int ry = ylo + rb + part;
                int lo = (ry & 1) ? (G - 1 - xhi) : xlo;
                int hi = (ry & 1) ? (G - 1 - xlo) : xhi;
                s0 = offsets[ry * G + lo];
                e0 = offsets[ry * G + hi + 1];
            }
            for (int rr = 0; rr < rem; ++rr) {
                int s = __shfl(s0, gb + rr);
                int e = __shfl(e0, gb + rr);
                for (int i = s + part; i < e; i += PARTS) {
                    float2 c2 = sxy[i];
                    float dx = qx - c2.x, dy = qy - c2.y;
                    float d2 = fmaf(dx, dx, dy * dy);
                    if (d2 < b[KP1 - 1]) {
#pragma unroll
                        for (int u = KP1 - 1; u >= 1; --u)
                            b[u] = __builtin_amdgcn_fmed3f(d2, b[u - 1], b[u]);
                        b[0] = fminf(b[0], d2);
                    }
                }
            }
        }
    };

    // count-first sizing per GROUP (divergent loops = max over groups)
    int R = 1, nxlo = 0, nxhi = 0, nylo = 0, nyhi = 0;
    bool sized = false;
    while (!__all(sized)) {
        if (!sized) {
            nxlo = max(cx - R, 0); nxhi = min(cx + R, G - 1);
            nylo = max(cy - R, 0); nyhi = min(cy + R, G - 1);
            const int nrows = nyhi - nylo + 1;
            int total = 0;
            for (int rb = 0; rb < nrows; rb += 16) {
                int r = rb + part, c = 0;
                if (r < nrows) {
                    int ry = nylo + r;
                    int lo = (ry & 1) ? (G - 1 - nxhi) : nxlo;
                    int hi = (ry & 1) ? (G - 1 - nxlo) : nxhi;
                    c = offsets[ry * G + hi + 1] - offsets[ry * G + lo];
                }
                c += __shfl_xor(c, 1); c += __shfl_xor(c, 2);
                c += __shfl_xor(c, 4); c += __shfl_xor(c, 8);
                total += c;
            }
            bool whole = (nxlo == 0 && nylo == 0 && nxhi == G - 1 && nyhi == G - 1);
            if (total >= TARGET || whole) sized = true;
            else R <<= 1;
        }
    }

    scan_rect(nylo, nyhi, nxlo, nxhi);   // one full-rect scan per group

    // stop check per group; on failure expand by disjoint delta strips
    bool done = false;
    while (!__all(done)) {
        if (!done) {
            float Xr = (float)R * HMIN;
            float X = Xr * Xr;
            int cnt = 0;
#pragma unroll
            for (int i = 0; i < KP1; ++i) cnt += (b[i] <= X) ? 1 : 0;
            cnt += __shfl_xor(cnt, 1); cnt += __shfl_xor(cnt, 2);
            cnt += __shfl_xor(cnt, 4); cnt += __shfl_xor(cnt, 8);
            bool whole = (nxlo == 0 && nylo == 0 && nxhi == G - 1 && nyhi == G - 1);
            if (cnt >= KP1 || whole) {
                done = true;
            } else {
                const int pxlo = nxlo, pxhi = nxhi, pylo = nylo, pyhi = nyhi;
                R <<= 1;
                nxlo = max(cx - R, 0); nxhi = min(cx + R, G - 1);
                nylo = max(cy - R, 0); nyhi = min(cy + R, G - 1);
                scan_rect(nylo, pylo - 1, nxlo, nxhi);   // top strip
                scan_rect(pyhi + 1, nyhi, nxlo, nxhi);   // bottom strip
                scan_rect(pylo, pyhi, nxlo, pxlo - 1);   // left strip
                scan_rect(pylo, pyhi, pxhi + 1, nxhi);   // right strip
            }
        }
    }

    // merge 16 partition lists per query (wave-local LDS, no block barrier)
    float* mm = &mrg[wv][ql][part][0];
#pragma unroll
    for (int i = 0; i < KP1; ++i) mm[i] = b[i];
    asm volatile("s_waitcnt lgkmcnt(0)" ::: "memory");
    __builtin_amdgcn_sched_barrier(0);

    if (part == 0 && sq < n) {
        for (int pp = 1; pp < PARTS; ++pp) {
            const float* src = &mrg[wv][ql][pp][0];
#pragma unroll 1
            for (int i = 0; i < KP1; ++i) {
                float d2 = src[i];
                if (d2 >= b[KP1 - 1]) break;   // ascending lists
#pragma unroll
                for (int u = KP1 - 1; u >= 1; --u)
                    b[u] = __builtin_amdgcn_fmed3f(d2, b[u - 1], b[u]);
                b[0] = fminf(b[0], d2);
            }
        }
        // b[0] == 0 (self); write 16 distances to the original row
        float4* op = (float4*)(out + (size_t)sidx[sq] * NK);
#pragma unroll
        for (int i = 0; i < 4; ++i)
            op[i] = make_float4(sqrtf(b[4 * i + 1]), sqrtf(b[4 * i + 2]),
                                sqrtf(b[4 * i + 3]), sqrtf(b[4 * i + 4]));
    }
}

extern "C" void kernel_launch(void* const* d_in, const int* in_sizes, int n_in,
                              void* d_out, int out_size, void* d_ws, size_t ws_size,
                              hipStream_t stream) {
    const float* p = (const float*)d_in[0];
    float* out = (float*)d_out;
    const int n = in_sizes[0] / 3;

    char* ws = (char*)d_ws;
    int*    counts  = (int*)(ws + WS_COUNTS);
    int*    bar     = (int*)(ws + WS_BAR);
    int*    bsum    = (int*)(ws + WS_BSUM);
    int*    offsets = (int*)(ws + WS_OFFSETS);
    float2* sxy     = (float2*)(ws + WS_SXY);
    int*    sidx    = (int*)(ws + WS_SIDX);

    // zero counts + barrier slots in one call
    hipMemsetAsync(counts, 0, 65600, stream);

    hipLaunchKernelGGL(build_kernel, dim3(NBB), dim3(1024), 0, stream,
                       p, n, counts, bar, bsum, offsets, sxy, sidx);

    const int nq = (n + QPW * 4 - 1) / (QPW * 4);   // waves of 4 queries, 4 waves/block
    hipLaunchKernelGGL(knn_query, dim3(nq), dim3(BLOCK), 0, stream,
                       offsets, sxy, sidx, out, n);
}

// Round 12
// 112.359 us; speedup vs baseline: 2.0007x; 2.0007x over previous
//
#include <hip/hip_runtime.h>
#include <math.h>

// 2D 16-NN distances, N=16384, exact, uniform-grid binned, fixed bounds.
// 3 dispatches: memset(cursor0) -> build (ONE kernel: per-block REDUNDANT
// LDS histogram + LDS scan of all 16K cells, then scatter own 1024 points;
// no inter-block sync needed) -> query.
// Build lesson (r10): device-scope fences/barriers cost ~30us on MI355X
// (per-XCD L2 writeback) — redundant parallel work is far cheaper.
// Query (r10, passed): each 16-LANE GROUP owns ONE query: own rect/R,
// count-first sizing, ONE rect scan w/ group-parallel span prefetch, own
// stop proof (>=17 pts incl self within R*HMIN <= dist to any unvisited
// cell), delta strips on rare failure. Per-lane sorted top-17 (med3 chain);
// self (d2=0) dropped at output == reference idx[:,1:].

#define G      128
#define NC     (G * G)
#define NK     16
#define KP1    17
#define QPW    4
#define PARTS  16
#define BLOCK  256
#define TARGET 48

#define BX0   (-5.5f)
#define BY0   (-5.5f)
#define BEXT  (11.0f)
#define IH    ((float)G * (1.0f - 1e-5f) / BEXT)   // cells per unit
#define HMIN  (BEXT / ((float)G * (1.0f - 1e-5f))) // cell dimension

// ws layout (bytes), total 327744 (< round-4's proven 393344)
#define WS_CURSOR0  0        // 16384 i32, zeroed by memset
#define WS_OFFSETS  65536    // 16385 i32
#define WS_SXY      131136   // 16384 float2
#define WS_SIDX     262208   // 16384 i32

__device__ __forceinline__ int clampi(int v, int lo, int hi) {
    return v < lo ? lo : (v > hi ? hi : v);
}
__device__ __forceinline__ int cell_of(float x, float y) {
    int cx = clampi((int)((x - BX0) * IH), 0, G - 1);
    int cy = clampi((int)((y - BY0) * IH), 0, G - 1);
    int xx = (cy & 1) ? (G - 1 - cx) : cx;     // serpentine
    return cy * G + xx;
}

// ---- build: per-block redundant LDS count+scan, then scatter own slice ----
__global__ __launch_bounds__(1024) void build_kernel(const float* __restrict__ p, int n,
                                                     int* __restrict__ cursor0,
                                                     int* __restrict__ offsets,
                                                     float2* __restrict__ sxy,
                                                     int* __restrict__ sidx) {
    __shared__ int hist[NC];      // 64 KB: counts -> exclusive offsets
    __shared__ int scn[1024];
    const int t   = threadIdx.x;
    const int gid = blockIdx.x * 1024 + t;

    for (int c = t; c < NC; c += 1024) hist[c] = 0;
    __syncthreads();

    // count ALL points (redundant per block); capture own point when k==blockIdx.x
    float myx = 0.f, myy = 0.f; int mycell = -1;
    for (int k = 0; k < 16; ++k) {
        int i = (k << 10) + t;
        if (i < n) {
            float x = p[3 * i], y = p[3 * i + 1];
            int c = cell_of(x, y);
            atomicAdd(&hist[c], 1);
            if (i == gid) { myx = x; myy = y; mycell = c; }
        }
    }
    __syncthreads();

    // exclusive prefix scan of 16384 cells (thread owns 16 consecutive)
    int loc[16]; int s = 0;
#pragma unroll
    for (int j = 0; j < 16; ++j) { loc[j] = hist[(t << 4) + j]; s += loc[j]; }
    scn[t] = s; __syncthreads();
    for (int off = 1; off < 1024; off <<= 1) {
        int v = (t >= off) ? scn[t - off] : 0;
        __syncthreads();
        scn[t] += v;
        __syncthreads();
    }
    int base = scn[t] - s;   // exclusive
#pragma unroll
    for (int j = 0; j < 16; ++j) {
        hist[(t << 4) + j] = base;   // hist becomes exclusive offsets
        base += loc[j];
    }
    __syncthreads();

    // block 0 publishes offsets for the query kernel
    if (blockIdx.x == 0) {
#pragma unroll
        for (int j = 0; j < 16; ++j) offsets[(t << 4) + j] = hist[(t << 4) + j];
        if (t == 1023) offsets[NC] = base;   // == n
    }

    // scatter own point (cross-block intra-cell slots via zeroed cursor0)
    if (mycell >= 0) {
        int pos = hist[mycell] + atomicAdd(&cursor0[mycell], 1);
        sxy[pos] = make_float2(myx, myy);
        sidx[pos] = gid;
    }
}

// ---- query: one 16-lane group per query, fully decoupled (r10, passed) ----
__global__ __launch_bounds__(BLOCK) void knn_query(const int* __restrict__ offsets,
                                                   const float2* __restrict__ sxy,
                                                   const int* __restrict__ sidx,
                                                   float* __restrict__ out, int n) {
    __shared__ float mrg[4][QPW][PARTS][KP1];

    const int t    = threadIdx.x;
    const int lane = t & 63;
    const int wv   = t >> 6;
    const int ql   = lane >> 4;      // group (query slot) 0..3
    const int part = lane & 15;
    const int gb   = ql << 4;        // group base lane
    const int sq   = (blockIdx.x * 4 + wv) * QPW + ql;
    const int sqc  = (sq < n) ? sq : (n - 1);

    const float2 qp = sxy[sqc];
    const float qx = qp.x, qy = qp.y;
    const int cx = clampi((int)((qx - BX0) * IH), 0, G - 1);
    const int cy = clampi((int)((qy - BY0) * IH), 0, G - 1);

    float b[KP1];
#pragma unroll
    for (int i = 0; i < KP1; ++i) b[i] = 3.0e38f;

    // group-parallel scan of cell rect [ylo..yhi]x[xlo..xhi]
    auto scan_rect = [&](int ylo, int yhi, int xlo, int xhi) {
        if (ylo > yhi || xlo > xhi) return;
        const int nrows = yhi - ylo + 1;
        for (int rb = 0; rb < nrows; rb += 16) {
            const int rem = min(nrows - rb, 16);   // group-uniform
            int s0 = 0, e0 = 0;
            if (part < rem) {
                int ry = ylo + rb + part;
                int lo = (ry & 1) ? (G - 1 - xhi) : xlo;
                int hi = (ry & 1) ? (G - 1 - xlo) : xhi;
                s0 = offsets[ry * G + lo];
                e0 = offsets[ry * G + hi + 1];
            }
            for (int rr = 0; rr < rem; ++rr) {
                int s = __shfl(s0, gb + rr);
                int e = __shfl(e0, gb + rr);
                for (int i = s + part; i < e; i += PARTS) {
                    float2 c2 = sxy[i];
                    float dx = qx - c2.x, dy = qy - c2.y;
                    float d2 = fmaf(dx, dx, dy * dy);
                    if (d2 < b[KP1 - 1]) {
#pragma unroll
                        for (int u = KP1 - 1; u >= 1; --u)
                            b[u] = __builtin_amdgcn_fmed3f(d2, b[u - 1], b[u]);
                        b[0] = fminf(b[0], d2);
                    }
                }
            }
        }
    };

    // count-first sizing per GROUP (divergent loops = max over groups)
    int R = 1, nxlo = 0, nxhi = 0, nylo = 0, nyhi = 0;
    bool sized = false;
    while (!__all(sized)) {
        if (!sized) {
            nxlo = max(cx - R, 0); nxhi = min(cx + R, G - 1);
            nylo = max(cy - R, 0); nyhi = min(cy + R, G - 1);
            const int nrows = nyhi - nylo + 1;
            int total = 0;
            for (int rb = 0; rb < nrows; rb += 16) {
                int r = rb + part, c = 0;
                if (r < nrows) {
                    int ry = nylo + r;
                    int lo = (ry & 1) ? (G - 1 - nxhi) : nxlo;
                    int hi = (ry & 1) ? (G - 1 - nxlo) : nxhi;
                    c = offsets[ry * G + hi + 1] - offsets[ry * G + lo];
                }
                c += __shfl_xor(c, 1); c += __shfl_xor(c, 2);
                c += __shfl_xor(c, 4); c += __shfl_xor(c, 8);
                total += c;
            }
            bool whole = (nxlo == 0 && nylo == 0 && nxhi == G - 1 && nyhi == G - 1);
            if (total >= TARGET || whole) sized = true;
            else R <<= 1;
        }
    }

    scan_rect(nylo, nyhi, nxlo, nxhi);   // one full-rect scan per group

    // stop check per group; on failure expand by disjoint delta strips
    bool done = false;
    while (!__all(done)) {
        if (!done) {
            float Xr = (float)R * HMIN;
            float X = Xr * Xr;
            int cnt = 0;
#pragma unroll
            for (int i = 0; i < KP1; ++i) cnt += (b[i] <= X) ? 1 : 0;
            cnt += __shfl_xor(cnt, 1); cnt += __shfl_xor(cnt, 2);
            cnt += __shfl_xor(cnt, 4); cnt += __shfl_xor(cnt, 8);
            bool whole = (nxlo == 0 && nylo == 0 && nxhi == G - 1 && nyhi == G - 1);
            if (cnt >= KP1 || whole) {
                done = true;
            } else {
                const int pxlo = nxlo, pxhi = nxhi, pylo = nylo, pyhi = nyhi;
                R <<= 1;
                nxlo = max(cx - R, 0); nxhi = min(cx + R, G - 1);
                nylo = max(cy - R, 0); nyhi = min(cy + R, G - 1);
                scan_rect(nylo, pylo - 1, nxlo, nxhi);   // top strip
                scan_rect(pyhi + 1, nyhi, nxlo, nxhi);   // bottom strip
                scan_rect(pylo, pyhi, nxlo, pxlo - 1);   // left strip
                scan_rect(pylo, pyhi, pxhi + 1, nxhi);   // right strip
            }
        }
    }

    // merge 16 partition lists per query (wave-local LDS, no block barrier)
    float* mm = &mrg[wv][ql][part][0];
#pragma unroll
    for (int i = 0; i < KP1; ++i) mm[i] = b[i];
    asm volatile("s_waitcnt lgkmcnt(0)" ::: "memory");
    __builtin_amdgcn_sched_barrier(0);

    if (part == 0 && sq < n) {
        for (int pp = 1; pp < PARTS; ++pp) {
            const float* src = &mrg[wv][ql][pp][0];
#pragma unroll 1
            for (int i = 0; i < KP1; ++i) {
                float d2 = src[i];
                if (d2 >= b[KP1 - 1]) break;   // ascending lists
#pragma unroll
                for (int u = KP1 - 1; u >= 1; --u)
                    b[u] = __builtin_amdgcn_fmed3f(d2, b[u - 1], b[u]);
                b[0] = fminf(b[0], d2);
            }
        }
        // b[0] == 0 (self); write 16 distances to the original row
        float4* op = (float4*)(out + (size_t)sidx[sq] * NK);
#pragma unroll
        for (int i = 0; i < 4; ++i)
            op[i] = make_float4(sqrtf(b[4 * i + 1]), sqrtf(b[4 * i + 2]),
                                sqrtf(b[4 * i + 3]), sqrtf(b[4 * i + 4]));
    }
}

extern "C" void kernel_launch(void* const* d_in, const int* in_sizes, int n_in,
                              void* d_out, int out_size, void* d_ws, size_t ws_size,
                              hipStream_t stream) {
    const float* p = (const float*)d_in[0];
    float* out = (float*)d_out;
    const int n = in_sizes[0] / 3;

    char* ws = (char*)d_ws;
    int*    cursor0 = (int*)(ws + WS_CURSOR0);
    int*    offsets = (int*)(ws + WS_OFFSETS);
    float2* sxy     = (float2*)(ws + WS_SXY);
    int*    sidx    = (int*)(ws + WS_SIDX);

    hipMemsetAsync(cursor0, 0, NC * sizeof(int), stream);

    const int nbb = (n + 1023) / 1024;   // 16 build blocks
    hipLaunchKernelGGL(build_kernel, dim3(nbb), dim3(1024), 0, stream,
                       p, n, cursor0, offsets, sxy, sidx);

    const int nq = (n + QPW * 4 - 1) / (QPW * 4);   // 16 queries per 256-thr block
    hipLaunchKernelGGL(knn_query, dim3(nq), dim3(BLOCK), 0, stream,
                       offsets, sxy, sidx, out, n);
}

// Round 13
// 112.092 us; speedup vs baseline: 2.0055x; 1.0024x over previous
//
#include <hip/hip_runtime.h>
#include <math.h>

// 2D 16-NN distances, N=16384, exact, uniform-grid binned, fixed bounds.
// TWO dispatches, no memset, no global cursor:
//   build: 16 blocks x 1024. Each block REDUNDANTLY histograms ALL points in
//     LDS (hist), plus a second LDS histogram (hist2) of points with index
//     < block_base -> deterministic non-overlapping scatter slots:
//     pos = offsets[cell] + (hist2[cell]++). Block 0 publishes offsets.
//     (r10 lesson: device-scope barriers ~30us on MI355X; redundancy wins.)
//   query (r11, passed, unchanged): each 16-LANE GROUP owns ONE query: own
//     rect/R, count-first sizing (TARGET pts), ONE rect scan w/ group-parallel
//     span prefetch, own stop proof (>=17 pts incl self within R*HMIN <= dist
//     to any unvisited cell), delta strips on rare failure. Per-lane sorted
//     top-17 (med3 chain); self (d2=0) dropped at output == ref idx[:,1:].

#define G      128
#define NC     (G * G)
#define NK     16
#define KP1    17
#define QPW    4
#define PARTS  16
#define BLOCK  256
#define TARGET 48

#define BX0   (-5.5f)
#define BY0   (-5.5f)
#define BEXT  (11.0f)
#define IH    ((float)G * (1.0f - 1e-5f) / BEXT)   // cells per unit
#define HMIN  (BEXT / ((float)G * (1.0f - 1e-5f))) // cell dimension

// ws layout (bytes), total 262212 (< round-4's proven 393344)
#define WS_OFFSETS  0        // 16385 i32
#define WS_SXY      65600    // 16384 float2
#define WS_SIDX     196672   // 16384 i32

__device__ __forceinline__ int clampi(int v, int lo, int hi) {
    return v < lo ? lo : (v > hi ? hi : v);
}
__device__ __forceinline__ int cell_of(float x, float y) {
    int cx = clampi((int)((x - BX0) * IH), 0, G - 1);
    int cy = clampi((int)((y - BY0) * IH), 0, G - 1);
    int xx = (cy & 1) ? (G - 1 - cx) : cx;     // serpentine
    return cy * G + xx;
}

// ---- build: redundant LDS hist + earlier-point hist2 -> scatter own slice ----
__global__ __launch_bounds__(1024) void build_kernel(const float* __restrict__ p, int n,
                                                     int* __restrict__ offsets,
                                                     float2* __restrict__ sxy,
                                                     int* __restrict__ sidx) {
    __shared__ int hist[NC];      // counts -> exclusive offsets (64 KB)
    __shared__ int hist2[NC];     // counts of points with idx < block_base (64 KB)
    __shared__ int scn[1024];
    const int t     = threadIdx.x;
    const int bbase = blockIdx.x << 10;
    const int gid   = bbase + t;
    const int nk    = (n + 1023) >> 10;

    for (int c = t; c < NC; c += 1024) { hist[c] = 0; hist2[c] = 0; }
    __syncthreads();

    // count ALL points; also count earlier-block points into hist2
    float myx = 0.f, myy = 0.f; int mycell = -1;
    for (int k = 0; k < nk; ++k) {
        int i = (k << 10) + t;
        if (i < n) {
            float x = p[3 * i], y = p[3 * i + 1];
            int c = cell_of(x, y);
            atomicAdd(&hist[c], 1);
            if (i < bbase) atomicAdd(&hist2[c], 1);
            if (i == gid) { myx = x; myy = y; mycell = c; }
        }
    }
    __syncthreads();

    // exclusive prefix scan of 16384 cells (thread owns 16 consecutive)
    int loc[16]; int s = 0;
#pragma unroll
    for (int j = 0; j < 16; ++j) { loc[j] = hist[(t << 4) + j]; s += loc[j]; }
    scn[t] = s; __syncthreads();
    for (int off = 1; off < 1024; off <<= 1) {
        int v = (t >= off) ? scn[t - off] : 0;
        __syncthreads();
        scn[t] += v;
        __syncthreads();
    }
    int base = scn[t] - s;   // exclusive
#pragma unroll
    for (int j = 0; j < 16; ++j) {
        hist[(t << 4) + j] = base;   // hist becomes exclusive offsets
        base += loc[j];
    }
    __syncthreads();

    // block 0 publishes offsets for the query kernel
    if (blockIdx.x == 0) {
#pragma unroll
        for (int j = 0; j < 16; ++j) offsets[(t << 4) + j] = hist[(t << 4) + j];
        if (t == 1023) offsets[NC] = base;   // == n
    }

    // scatter own point: slot base = earlier-block count (hist2), all in LDS
    if (mycell >= 0) {
        int pos = hist[mycell] + atomicAdd(&hist2[mycell], 1);
        sxy[pos] = make_float2(myx, myy);
        sidx[pos] = gid;
    }
}

// ---- query: one 16-lane group per query, fully decoupled (r11, passed) ----
__global__ __launch_bounds__(BLOCK) void knn_query(const int* __restrict__ offsets,
                                                   const float2* __restrict__ sxy,
                                                   const int* __restrict__ sidx,
                                                   float* __restrict__ out, int n) {
    __shared__ float mrg[4][QPW][PARTS][KP1];

    const int t    = threadIdx.x;
    const int lane = t & 63;
    const int wv   = t >> 6;
    const int ql   = lane >> 4;      // group (query slot) 0..3
    const int part = lane & 15;
    const int gb   = ql << 4;        // group base lane
    const int sq   = (blockIdx.x * 4 + wv) * QPW + ql;
    const int sqc  = (sq < n) ? sq : (n - 1);

    const float2 qp = sxy[sqc];
    const float qx = qp.x, qy = qp.y;
    const int cx = clampi((int)((qx - BX0) * IH), 0, G - 1);
    const int cy = clampi((int)((qy - BY0) * IH), 0, G - 1);

    float b[KP1];
#pragma unroll
    for (int i = 0; i < KP1; ++i) b[i] = 3.0e38f;

    // group-parallel scan of cell rect [ylo..yhi]x[xlo..xhi]
    auto scan_rect = [&](int ylo, int yhi, int xlo, int xhi) {
        if (ylo > yhi || xlo > xhi) return;
        const int nrows = yhi - ylo + 1;
        for (int rb = 0; rb < nrows; rb += 16) {
            const int rem = min(nrows - rb, 16);   // group-uniform
            int s0 = 0, e0 = 0;
            if (part < rem) {
                int ry = ylo + rb + part;
                int lo = (ry & 1) ? (G - 1 - xhi) : xlo;
                int hi = (ry & 1) ? (G - 1 - xlo) : xhi;
                s0 = offsets[ry * G + lo];
                e0 = offsets[ry * G + hi + 1];
            }
            for (int rr = 0; rr < rem; ++rr) {
                int s = __shfl(s0, gb + rr);
                int e = __shfl(e0, gb + rr);
                for (int i = s + part; i < e; i += PARTS) {
                    float2 c2 = sxy[i];
                    float dx = qx - c2.x, dy = qy - c2.y;
                    float d2 = fmaf(dx, dx, dy * dy);
                    if (d2 < b[KP1 - 1]) {
#pragma unroll
                        for (int u = KP1 - 1; u >= 1; --u)
                            b[u] = __builtin_amdgcn_fmed3f(d2, b[u - 1], b[u]);
                        b[0] = fminf(b[0], d2);
                    }
                }
            }
        }
    };

    // count-first sizing per GROUP (divergent loops = max over groups)
    int R = 1, nxlo = 0, nxhi = 0, nylo = 0, nyhi = 0;
    bool sized = false;
    while (!__all(sized)) {
        if (!sized) {
            nxlo = max(cx - R, 0); nxhi = min(cx + R, G - 1);
            nylo = max(cy - R, 0); nyhi = min(cy + R, G - 1);
            const int nrows = nyhi - nylo + 1;
            int total = 0;
            for (int rb = 0; rb < nrows; rb += 16) {
                int r = rb + part, c = 0;
                if (r < nrows) {
                    int ry = nylo + r;
                    int lo = (ry & 1) ? (G - 1 - nxhi) : nxlo;
                    int hi = (ry & 1) ? (G - 1 - nxlo) : nxhi;
                    c = offsets[ry * G + hi + 1] - offsets[ry * G + lo];
                }
                c += __shfl_xor(c, 1); c += __shfl_xor(c, 2);
                c += __shfl_xor(c, 4); c += __shfl_xor(c, 8);
                total += c;
            }
            bool whole = (nxlo == 0 && nylo == 0 && nxhi == G - 1 && nyhi == G - 1);
            if (total >= TARGET || whole) sized = true;
            else R <<= 1;
        }
    }

    scan_rect(nylo, nyhi, nxlo, nxhi);   // one full-rect scan per group

    // stop check per group; on failure expand by disjoint delta strips
    bool done = false;
    while (!__all(done)) {
        if (!done) {
            float Xr = (float)R * HMIN;
            float X = Xr * Xr;
            int cnt = 0;
#pragma unroll
            for (int i = 0; i < KP1; ++i) cnt += (b[i] <= X) ? 1 : 0;
            cnt += __shfl_xor(cnt, 1); cnt += __shfl_xor(cnt, 2);
            cnt += __shfl_xor(cnt, 4); cnt += __shfl_xor(cnt, 8);
            bool whole = (nxlo == 0 && nylo == 0 && nxhi == G - 1 && nyhi == G - 1);
            if (cnt >= KP1 || whole) {
                done = true;
            } else {
                const int pxlo = nxlo, pxhi = nxhi, pylo = nylo, pyhi = nyhi;
                R <<= 1;
                nxlo = max(cx - R, 0); nxhi = min(cx + R, G - 1);
                nylo = max(cy - R, 0); nyhi = min(cy + R, G - 1);
                scan_rect(nylo, pylo - 1, nxlo, nxhi);   // top strip
                scan_rect(pyhi + 1, nyhi, nxlo, nxhi);   // bottom strip
                scan_rect(pylo, pyhi, nxlo, pxlo - 1);   // left strip
                scan_rect(pylo, pyhi, pxhi + 1, nxhi);   // right strip
            }
        }
    }

    // merge 16 partition lists per query (wave-local LDS, no block barrier)
    float* mm = &mrg[wv][ql][part][0];
#pragma unroll
    for (int i = 0; i < KP1; ++i) mm[i] = b[i];
    asm volatile("s_waitcnt lgkmcnt(0)" ::: "memory");
    __builtin_amdgcn_sched_barrier(0);

    if (part == 0 && sq < n) {
        for (int pp = 1; pp < PARTS; ++pp) {
            const float* src = &mrg[wv][ql][pp][0];
#pragma unroll 1
            for (int i = 0; i < KP1; ++i) {
                float d2 = src[i];
                if (d2 >= b[KP1 - 1]) break;   // ascending lists
#pragma unroll
                for (int u = KP1 - 1; u >= 1; --u)
                    b[u] = __builtin_amdgcn_fmed3f(d2, b[u - 1], b[u]);
                b[0] = fminf(b[0], d2);
            }
        }
        // b[0] == 0 (self); write 16 distances to the original row
        float4* op = (float4*)(out + (size_t)sidx[sq] * NK);
#pragma unroll
        for (int i = 0; i < 4; ++i)
            op[i] = make_float4(sqrtf(b[4 * i + 1]), sqrtf(b[4 * i + 2]),
                                sqrtf(b[4 * i + 3]), sqrtf(b[4 * i + 4]));
    }
}

extern "C" void kernel_launch(void* const* d_in, const int* in_sizes, int n_in,
                              void* d_out, int out_size, void* d_ws, size_t ws_size,
                              hipStream_t stream) {
    const float* p = (const float*)d_in[0];
    float* out = (float*)d_out;
    const int n = in_sizes[0] / 3;

    char* ws = (char*)d_ws;
    int*    offsets = (int*)(ws + WS_OFFSETS);
    float2* sxy     = (float2*)(ws + WS_SXY);
    int*    sidx    = (int*)(ws + WS_SIDX);

    const int nbb = (n + 1023) / 1024;   // 16 build blocks
    hipLaunchKernelGGL(build_kernel, dim3(nbb), dim3(1024), 0, stream,
                       p, n, offsets, sxy, sidx);

    const int nq = (n + QPW * 4 - 1) / (QPW * 4);   // 16 queries per 256-thr block
    hipLaunchKernelGGL(knn_query, dim3(nq), dim3(BLOCK), 0, stream,
                       offsets, sxy, sidx, out, n);
}

// Round 14
// 109.138 us; speedup vs baseline: 2.0598x; 1.0271x over previous
//
#include <hip/hip_runtime.h>
#include <math.h>

// 2D 16-NN distances, N=16384, exact, uniform-grid binned, fixed bounds.
// TWO dispatches:
//   build (r12, proven): 16 blocks x 1024, per-block REDUNDANT LDS histogram
//     (hist) + earlier-point histogram (hist2) -> deterministic collision-free
//     scatter, no cross-block state. Block 0 publishes offsets.
//   query: each 16-LANE GROUP owns ONE query. Count-first R sizing (TARGET
//     pts in rect), then PRUNED NEAR-FIRST rect scan: rows enumerated
//     center-out; row skipped if dxmin_rect^2+dymin_row^2 > b[16] (exact:
//     such rows cannot enter the top-17); scan breaks when all remaining
//     rows prunable. Stop proof: >=17 pts (incl self) within R*HMIN <= dist
//     to any unvisited cell; delta strips (also pruned) on rare failure.
// Per-lane sorted top-17 via med3 chain; self (d2=0) dropped at output
// == reference idx[:,1:]. r10 lesson: no device-scope barriers (~30us).

#define G      128
#define NC     (G * G)
#define NK     16
#define KP1    17
#define QPW    4
#define PARTS  16
#define BLOCK  256
#define TARGET 48

#define BX0   (-5.5f)
#define BY0   (-5.5f)
#define BEXT  (11.0f)
#define IH    ((float)G * (1.0f - 1e-5f) / BEXT)   // cells per unit
#define H     (BEXT / ((float)G * (1.0f - 1e-5f))) // cell dimension

// ws layout (bytes), total 262212 (< round-4's proven 393344)
#define WS_OFFSETS  0        // 16385 i32
#define WS_SXY      65600    // 16384 float2
#define WS_SIDX     196672   // 16384 i32

__device__ __forceinline__ int clampi(int v, int lo, int hi) {
    return v < lo ? lo : (v > hi ? hi : v);
}
__device__ __forceinline__ int cell_of(float x, float y) {
    int cx = clampi((int)((x - BX0) * IH), 0, G - 1);
    int cy = clampi((int)((y - BY0) * IH), 0, G - 1);
    int xx = (cy & 1) ? (G - 1 - cx) : cx;     // serpentine
    return cy * G + xx;
}

// ---- build: redundant LDS hist + earlier-point hist2 -> scatter own slice ----
__global__ __launch_bounds__(1024) void build_kernel(const float* __restrict__ p, int n,
                                                     int* __restrict__ offsets,
                                                     float2* __restrict__ sxy,
                                                     int* __restrict__ sidx) {
    __shared__ int hist[NC];      // counts -> exclusive offsets (64 KB)
    __shared__ int hist2[NC];     // counts of points with idx < block_base (64 KB)
    __shared__ int scn[1024];
    const int t     = threadIdx.x;
    const int bbase = blockIdx.x << 10;
    const int gid   = bbase + t;
    const int nk    = (n + 1023) >> 10;

    for (int c = t; c < NC; c += 1024) { hist[c] = 0; hist2[c] = 0; }
    __syncthreads();

    float myx = 0.f, myy = 0.f; int mycell = -1;
    for (int k = 0; k < nk; ++k) {
        int i = (k << 10) + t;
        if (i < n) {
            float x = p[3 * i], y = p[3 * i + 1];
            int c = cell_of(x, y);
            atomicAdd(&hist[c], 1);
            if (i < bbase) atomicAdd(&hist2[c], 1);
            if (i == gid) { myx = x; myy = y; mycell = c; }
        }
    }
    __syncthreads();

    int loc[16]; int s = 0;
#pragma unroll
    for (int j = 0; j < 16; ++j) { loc[j] = hist[(t << 4) + j]; s += loc[j]; }
    scn[t] = s; __syncthreads();
    for (int off = 1; off < 1024; off <<= 1) {
        int v = (t >= off) ? scn[t - off] : 0;
        __syncthreads();
        scn[t] += v;
        __syncthreads();
    }
    int base = scn[t] - s;   // exclusive
#pragma unroll
    for (int j = 0; j < 16; ++j) {
        hist[(t << 4) + j] = base;   // hist becomes exclusive offsets
        base += loc[j];
    }
    __syncthreads();

    if (blockIdx.x == 0) {
#pragma unroll
        for (int j = 0; j < 16; ++j) offsets[(t << 4) + j] = hist[(t << 4) + j];
        if (t == 1023) offsets[NC] = base;   // == n
    }

    if (mycell >= 0) {
        int pos = hist[mycell] + atomicAdd(&hist2[mycell], 1);
        sxy[pos] = make_float2(myx, myy);
        sidx[pos] = gid;
    }
}

// ---- query: one 16-lane group per query; pruned near-first scan ----
__global__ __launch_bounds__(BLOCK) void knn_query(const int* __restrict__ offsets,
                                                   const float2* __restrict__ sxy,
                                                   const int* __restrict__ sidx,
                                                   float* __restrict__ out, int n) {
    __shared__ float mrg[4][QPW][PARTS][KP1];

    const int t    = threadIdx.x;
    const int lane = t & 63;
    const int wv   = t >> 6;
    const int ql   = lane >> 4;      // group (query slot) 0..3
    const int part = lane & 15;
    const int gb   = ql << 4;        // group base lane
    const int sq   = (blockIdx.x * 4 + wv) * QPW + ql;
    const int sqc  = (sq < n) ? sq : (n - 1);

    const float2 qp = sxy[sqc];
    const float qx = qp.x, qy = qp.y;
    const int cx = clampi((int)((qx - BX0) * IH), 0, G - 1);
    const int cy = clampi((int)((qy - BY0) * IH), 0, G - 1);

    float b[KP1];
#pragma unroll
    for (int i = 0; i < KP1; ++i) b[i] = 3.0e38f;

    // pruned, near-first scan of cell rect [ylo..yhi]x[xlo..xhi].
    // Rows enumerated center-out from clamp(cy); row skipped when
    // dxmin_rect^2 + dymin_row^2 > b[16] (cannot enter top-17: EXACT).
    auto scan_rect = [&](int ylo, int yhi, int xlo, int xhi) {
        if (ylo > yhi || xlo > xhi) return;
        const int cyc = clampi(cy, ylo, yhi);
        const int nb = cyc - ylo, na = yhi - cyc;
        const int mm2 = 2 * min(nb, na);
        const float xlo_f = BX0 + (float)xlo * H;
        const float xhi_f = BX0 + (float)(xhi + 1) * H;
        const float dx0 = fmaxf(0.f, fmaxf(xlo_f - qx, qx - xhi_f));
        const float dx2 = dx0 * dx0;
        const int nrows = yhi - ylo + 1;
        for (int kb = 0; kb < nrows; kb += 16) {
            // all remaining rows have |ry-cyc| >= dyb -> conservative break
            int dyb = (kb == 0) ? 0 : ((kb <= mm2) ? ((kb + 1) >> 1)
                                                   : (min(nb, na) + kb - mm2));
            float rem = fmaxf(0.f, (float)(dyb - 1)) * H;
            if (dx2 + rem * rem > b[KP1 - 1] * 1.0001f + 1e-10f) break;
            const int rem_rows = min(nrows - kb, 16);
            int s0 = 0, e0 = 0, myrow = 0;
            if (part < rem_rows) {
                const int k = kb + part;
                myrow = (k == 0) ? cyc
                      : (k <= mm2) ? ((k & 1) ? (cyc - ((k + 1) >> 1)) : (cyc + (k >> 1)))
                      : ((na > nb) ? (cyc + min(nb, na) + (k - mm2))
                                   : (cyc - min(nb, na) - (k - mm2)));
                int lo = (myrow & 1) ? (G - 1 - xhi) : xlo;
                int hi = (myrow & 1) ? (G - 1 - xlo) : xhi;
                s0 = offsets[myrow * G + lo];
                e0 = offsets[myrow * G + hi + 1];
            }
            for (int rr = 0; rr < rem_rows; ++rr) {
                const int s  = __shfl(s0, gb + rr);
                const int e  = __shfl(e0, gb + rr);
                if (s >= e) continue;
                const int rw = __shfl(myrow, gb + rr);
                const float ry0 = BY0 + (float)rw * H;
                const float dyr = fmaxf(0.f, fmaxf(ry0 - qy, qy - (ry0 + H)));
                if (dx2 + dyr * dyr > b[KP1 - 1] * 1.0001f + 1e-10f) continue;
                for (int i = s + part; i < e; i += PARTS) {
                    float2 c2 = sxy[i];
                    float dx = qx - c2.x, dy = qy - c2.y;
                    float d2 = fmaf(dx, dx, dy * dy);
                    if (d2 < b[KP1 - 1]) {
#pragma unroll
                        for (int u = KP1 - 1; u >= 1; --u)
                            b[u] = __builtin_amdgcn_fmed3f(d2, b[u - 1], b[u]);
                        b[0] = fminf(b[0], d2);
                    }
                }
            }
        }
    };

    // count-first sizing per GROUP (divergent loops = max over groups)
    int R = 1, nxlo = 0, nxhi = 0, nylo = 0, nyhi = 0;
    bool sized = false;
    while (!__all(sized)) {
        if (!sized) {
            nxlo = max(cx - R, 0); nxhi = min(cx + R, G - 1);
            nylo = max(cy - R, 0); nyhi = min(cy + R, G - 1);
            const int nrows = nyhi - nylo + 1;
            int total = 0;
            for (int rb = 0; rb < nrows; rb += 16) {
                int r = rb + part, c = 0;
                if (r < nrows) {
                    int ry = nylo + r;
                    int lo = (ry & 1) ? (G - 1 - nxhi) : nxlo;
                    int hi = (ry & 1) ? (G - 1 - nxlo) : nxhi;
                    c = offsets[ry * G + hi + 1] - offsets[ry * G + lo];
                }
                c += __shfl_xor(c, 1); c += __shfl_xor(c, 2);
                c += __shfl_xor(c, 4); c += __shfl_xor(c, 8);
                total += c;
            }
            bool whole = (nxlo == 0 && nylo == 0 && nxhi == G - 1 && nyhi == G - 1);
            if (total >= TARGET || whole) sized = true;
            else R <<= 1;
        }
    }

    scan_rect(nylo, nyhi, nxlo, nxhi);   // pruned full-rect scan

    // stop check per group; on failure expand by disjoint (pruned) strips
    bool done = false;
    while (!__all(done)) {
        if (!done) {
            float Xr = (float)R * H;
            float X = Xr * Xr;
            int cnt = 0;
#pragma unroll
            for (int i = 0; i < KP1; ++i) cnt += (b[i] <= X) ? 1 : 0;
            cnt += __shfl_xor(cnt, 1); cnt += __shfl_xor(cnt, 2);
            cnt += __shfl_xor(cnt, 4); cnt += __shfl_xor(cnt, 8);
            bool whole = (nxlo == 0 && nylo == 0 && nxhi == G - 1 && nyhi == G - 1);
            if (cnt >= KP1 || whole) {
                done = true;
            } else {
                const int pxlo = nxlo, pxhi = nxhi, pylo = nylo, pyhi = nyhi;
                R <<= 1;
                nxlo = max(cx - R, 0); nxhi = min(cx + R, G - 1);
                nylo = max(cy - R, 0); nyhi = min(cy + R, G - 1);
                scan_rect(nylo, pylo - 1, nxlo, nxhi);   // top strip
                scan_rect(pyhi + 1, nyhi, nxlo, nxhi);   // bottom strip
                scan_rect(pylo, pyhi, nxlo, pxlo - 1);   // left strip
                scan_rect(pylo, pyhi, pxhi + 1, nxhi);   // right strip
            }
        }
    }

    // merge 16 partition lists per query (wave-local LDS, no block barrier)
    float* mm = &mrg[wv][ql][part][0];
#pragma unroll
    for (int i = 0; i < KP1; ++i) mm[i] = b[i];
    asm volatile("s_waitcnt lgkmcnt(0)" ::: "memory");
    __builtin_amdgcn_sched_barrier(0);

    if (part == 0 && sq < n) {
        for (int pp = 1; pp < PARTS; ++pp) {
            const float* src = &mrg[wv][ql][pp][0];
#pragma unroll 1
            for (int i = 0; i < KP1; ++i) {
                float d2 = src[i];
                if (d2 >= b[KP1 - 1]) break;   // ascending lists
#pragma unroll
                for (int u = KP1 - 1; u >= 1; --u)
                    b[u] = __builtin_amdgcn_fmed3f(d2, b[u - 1], b[u]);
                b[0] = fminf(b[0], d2);
            }
        }
        // b[0] == 0 (self); write 16 distances to the original row
        float4* op = (float4*)(out + (size_t)sidx[sq] * NK);
#pragma unroll
        for (int i = 0; i < 4; ++i)
            op[i] = make_float4(sqrtf(b[4 * i + 1]), sqrtf(b[4 * i + 2]),
                                sqrtf(b[4 * i + 3]), sqrtf(b[4 * i + 4]));
    }
}

extern "C" void kernel_launch(void* const* d_in, const int* in_sizes, int n_in,
                              void* d_out, int out_size, void* d_ws, size_t ws_size,
                              hipStream_t stream) {
    const float* p = (const float*)d_in[0];
    float* out = (float*)d_out;
    const int n = in_sizes[0] / 3;

    char* ws = (char*)d_ws;
    int*    offsets = (int*)(ws + WS_OFFSETS);
    float2* sxy     = (float2*)(ws + WS_SXY);
    int*    sidx    = (int*)(ws + WS_SIDX);

    const int nbb = (n + 1023) / 1024;   // 16 build blocks
    hipLaunchKernelGGL(build_kernel, dim3(nbb), dim3(1024), 0, stream,
                       p, n, offsets, sxy, sidx);

    const int nq = (n + QPW * 4 - 1) / (QPW * 4);   // 16 queries per 256-thr block
    hipLaunchKernelGGL(knn_query, dim3(nq), dim3(BLOCK), 0, stream,
                       offsets, sxy, sidx, out, n);
}